// Round 5
// baseline (500.444 us; speedup 1.0000x reference)
//
#include <hip/hip_runtime.h>
#include <math.h>

// TokenChoiceRouter: B=8, T=8192, D=512 — single fused launch.
// d_out (float32 flat): [selected B*max_k][gate_weights B*max_k][raw_logits B*T][aux][z]
// ws: [done counter (64B)] [se f32 x16384] [sg f32 x16384]

#define TT 8192
#define BB 8
#define NB 32          // compaction roles per row
#define SLICE 256      // tokens per compaction slice
#define NPART 16384    // grid size (= BT/4)
#define NTAIL 257      // 256 compaction roles + 1 scalar role

__global__ __launch_bounds__(256) void fused_kernel(
    const float* __restrict__ x, const float* __restrict__ W,
    float* __restrict__ logits,
    float* __restrict__ ws_se, float* __restrict__ ws_sg,
    unsigned int* done,
    float* __restrict__ out_sel, float* __restrict__ out_gw,
    float* __restrict__ out_aux, float* __restrict__ out_z, int max_k)
{
    const int tid  = threadIdx.x;
    const int lane = tid & 63;
    const int wid  = tid >> 6;
    const int tok  = blockIdx.x * 4 + wid;

    __shared__ float s_lg[4];
    __shared__ unsigned int s_ticket;

    // ================= phase 1: wave-per-token logits (proven) ==============
    {
        const float4* xp = reinterpret_cast<const float4*>(x + (size_t)tok * 512 + lane * 8);
        const float4* wp = reinterpret_cast<const float4*>(W + lane * 8);
        float4 x0 = xp[0]; float4 x1 = xp[1];
        float4 w0 = wp[0]; float4 w1 = wp[1];

        double acc = (double)x0.x * w0.x + (double)x0.y * w0.y
                   + (double)x0.z * w0.z + (double)x0.w * w0.w
                   + (double)x1.x * w1.x + (double)x1.y * w1.y
                   + (double)x1.z * w1.z + (double)x1.w * w1.w;

        #pragma unroll
        for (int off = 32; off > 0; off >>= 1)
            acc += __shfl_xor(acc, off, 64);

        if (lane == 0) {
            const float lg = (float)acc;
            logits[tok] = lg;
            s_lg[wid] = lg;
        }
    }
    __syncthreads();   // drains all waves' global stores (vmcnt0) + s_lg visible
    if (tid == 0) {
        float se = 0.f, sg = 0.f;
        #pragma unroll
        for (int i = 0; i < 4; ++i) {
            const float lg = s_lg[i];
            se += expf(lg);
            sg += 1.f / (1.f + expf(-lg));
        }
        ws_se[blockIdx.x] = se;
        ws_sg[blockIdx.x] = sg;
        __threadfence();                       // release: L2 writeback, agent scope
        s_ticket = atomicAdd(done, 1u);        // device-scope
    }
    __syncthreads();
    const unsigned int ticket = s_ticket;
    if (ticket < (unsigned)(NPART - NTAIL)) return;

    // ================= phase 2: last 257 finishers do the tail ==============
    if (tid == 0) {
        while (__hip_atomic_load(done, __ATOMIC_ACQUIRE, __HIP_MEMORY_SCOPE_AGENT)
               < (unsigned)NPART)
            __builtin_amdgcn_s_sleep(2);
        __threadfence();                       // acquire: invalidate stale cache
    }
    __syncthreads();
    const int role = (int)ticket - (NPART - NTAIL);   // 0..256

    if (role == 256) {
        // ---- scalar losses from ws partials ----
        float acc8[8];
        #pragma unroll
        for (int r = 0; r < 8; ++r) {
            float s = 0.f;
            #pragma unroll
            for (int k = 0; k < 8; ++k) s += ws_se[r * 2048 + tid + 256 * k];
            acc8[r] = s;
        }
        float sgp = 0.f;
        #pragma unroll
        for (int k = 0; k < 64; ++k) sgp += ws_sg[tid + 256 * k];

        __shared__ float red[9][256];
        #pragma unroll
        for (int r = 0; r < 8; ++r) red[r][tid] = acc8[r];
        red[8][tid] = sgp;
        __syncthreads();
        for (int s = 128; s > 0; s >>= 1) {
            if (tid < s) {
                #pragma unroll
                for (int r = 0; r < 9; ++r) red[r][tid] += red[r][tid + s];
            }
            __syncthreads();
        }
        if (tid == 0) {
            float zz = 0.f;
            #pragma unroll
            for (int r = 0; r < 8; ++r) { float z = logf(red[r][0]); zz += z * z; }
            *out_z = 0.001f * zz / (float)BB;
            float m = red[8][0] / (float)(BB * TT);
            *out_aux = 0.01f * m * (1.f - m);
        }
        return;
    }

    // ---- per-row stable compaction; role owns a 256-token output slice ----
    const int row  = role >> 5;   // /NB
    const int part = role & 31;   // %NB
    const float* rowp = logits + (size_t)row * TT;

    const int base = 32 * tid;
    float4 v0 = *reinterpret_cast<const float4*>(rowp + base);
    float4 v1 = *reinterpret_cast<const float4*>(rowp + base + 4);
    float4 v2 = *reinterpret_cast<const float4*>(rowp + base + 8);
    float4 v3 = *reinterpret_cast<const float4*>(rowp + base + 12);
    float4 v4 = *reinterpret_cast<const float4*>(rowp + base + 16);
    float4 v5 = *reinterpret_cast<const float4*>(rowp + base + 20);
    float4 v6 = *reinterpret_cast<const float4*>(rowp + base + 24);
    float4 v7 = *reinterpret_cast<const float4*>(rowp + base + 28);

    unsigned mask = 0u;
#define CHK(f, b) mask |= ((f >= 0.f) ? 1u : 0u) << (b)
    CHK(v0.x, 0);  CHK(v0.y, 1);  CHK(v0.z, 2);  CHK(v0.w, 3);
    CHK(v1.x, 4);  CHK(v1.y, 5);  CHK(v1.z, 6);  CHK(v1.w, 7);
    CHK(v2.x, 8);  CHK(v2.y, 9);  CHK(v2.z, 10); CHK(v2.w, 11);
    CHK(v3.x, 12); CHK(v3.y, 13); CHK(v3.z, 14); CHK(v3.w, 15);
    CHK(v4.x, 16); CHK(v4.y, 17); CHK(v4.z, 18); CHK(v4.w, 19);
    CHK(v5.x, 20); CHK(v5.y, 21); CHK(v5.z, 22); CHK(v5.w, 23);
    CHK(v6.x, 24); CHK(v6.y, 25); CHK(v6.z, 26); CHK(v6.w, 27);
    CHK(v7.x, 28); CHK(v7.y, 29); CHK(v7.z, 30); CHK(v7.w, 31);
#undef CHK
    const int c_local = __popc(mask);

    int inc = c_local;
    #pragma unroll
    for (int off = 1; off < 64; off <<= 1) {
        int n = __shfl_up(inc, off, 64);
        if (lane >= off) inc += n;
    }
    __shared__ int s_wsum[4];
    __shared__ int s_last[4];
    __shared__ int s_excl[256];
    if (lane == 63) s_wsum[wid] = inc;

    int lastt = mask ? (base + 31 - __clz(mask)) : -1;
    #pragma unroll
    for (int off = 32; off > 0; off >>= 1)
        lastt = max(lastt, __shfl_xor(lastt, off, 64));
    if (lane == 0) s_last[wid] = lastt;
    __syncthreads();

    int woff = 0;
    #pragma unroll
    for (int w = 0; w < 4; ++w) if (w < wid) woff += s_wsum[w];
    const int cnt = s_wsum[0] + s_wsum[1] + s_wsum[2] + s_wsum[3];
    const int excl = woff + (inc - c_local);
    s_excl[tid] = excl;
    const int tok_last = max(max(s_last[0], s_last[1]), max(s_last[2], s_last[3]));
    __syncthreads();

    const int slice0 = s_excl[8 * part];
    const int slice1 = (part == NB - 1) ? cnt : s_excl[8 * part + 8];

    __shared__ unsigned short s_tok[SLICE];
    __shared__ float          s_gwv[SLICE];
    if (tid >= 8 * part && tid < 8 * part + 8) {
        int off = excl - slice0;
#define EMIT(f, i) if ((f) >= 0.f) { s_tok[off] = (unsigned short)(base + (i)); \
                                     s_gwv[off] = 1.f / (1.f + expf(-(f))); ++off; }
        EMIT(v0.x, 0);  EMIT(v0.y, 1);  EMIT(v0.z, 2);  EMIT(v0.w, 3);
        EMIT(v1.x, 4);  EMIT(v1.y, 5);  EMIT(v1.z, 6);  EMIT(v1.w, 7);
        EMIT(v2.x, 8);  EMIT(v2.y, 9);  EMIT(v2.z, 10); EMIT(v2.w, 11);
        EMIT(v3.x, 12); EMIT(v3.y, 13); EMIT(v3.z, 14); EMIT(v3.w, 15);
        EMIT(v4.x, 16); EMIT(v4.y, 17); EMIT(v4.z, 18); EMIT(v4.w, 19);
        EMIT(v5.x, 20); EMIT(v5.y, 21); EMIT(v5.z, 22); EMIT(v5.w, 23);
        EMIT(v6.x, 24); EMIT(v6.y, 25); EMIT(v6.z, 26); EMIT(v6.w, 27);
        EMIT(v7.x, 28); EMIT(v7.y, 29); EMIT(v7.z, 30); EMIT(v7.w, 31);
#undef EMIT
    }
    __syncthreads();

    const int m = slice1 - slice0;
    if (tid < m) {
        out_sel[(size_t)row * max_k + slice0 + tid] = (float)s_tok[tid];
        out_gw [(size_t)row * max_k + slice0 + tid] = s_gwv[tid];
    }

    const int tl = (cnt > 0) ? tok_last : 0;
    const float gw_last = 1.f / (1.f + expf(-rowp[tl]));
    for (int k = cnt + part * SLICE + tid; k < max_k; k += NB * SLICE) {
        out_sel[(size_t)row * max_k + k] = (float)tl;
        out_gw [(size_t)row * max_k + k] = gw_last;
    }
}

extern "C" void kernel_launch(void* const* d_in, const int* in_sizes, int n_in,
                              void* d_out, int out_size, void* d_ws, size_t ws_size,
                              hipStream_t stream)
{
    const float* x = (const float*)d_in[0];
    const float* W = (const float*)d_in[1];

    const int D  = in_sizes[1];          // 512
    const int BT = in_sizes[0] / D;      // 65536
    const int max_k = (out_size - BT - 2) / (2 * BB);

    float* out        = (float*)d_out;
    float* out_sel    = out;
    float* out_gw     = out + (size_t)BB * max_k;
    float* out_logits = out + (size_t)2 * BB * max_k;
    float* out_aux    = out + (size_t)2 * BB * max_k + BT;
    float* out_z      = out_aux + 1;

    unsigned int* done = (unsigned int*)d_ws;
    float* ws_se = (float*)((char*)d_ws + 64);
    float* ws_sg = ws_se + NPART;

    // Reset the finish counter every call (ws is poisoned, never re-poisoned).
    hipMemsetAsync(d_ws, 0, 64, stream);

    fused_kernel<<<NPART, 256, 0, stream>>>(x, W, out_logits, ws_se, ws_sg,
                                            done, out_sel, out_gw,
                                            out_aux, out_z, max_k);
}

// Round 7
// 220.741 us; speedup vs baseline: 2.2671x; 2.2671x over previous
//
#include <hip/hip_runtime.h>
#include <math.h>

// TokenChoiceRouter: B=8, T=8192, D=512 — single fused launch, ticket tail.
// d_out (float32 flat): [selected B*max_k][gate_weights B*max_k][raw_logits B*T][aux][z]
// ws: [done counter (64B)] [se f32 x16384] [sg f32 x16384]
//
// gfx950 cross-XCD rules learned in r5/r6:
//   r5: per-block __threadfence (wbl2) + per-poll ACQUIRE loads (buffer_inv)
//       -> 660us. NEVER flush/inv in the per-block fast path.
//   r6: RELAXED agent atomic LOAD spin never saw the counter -> hang.
//       Relaxed agent loads can be served stale on gfx950.
//   Fix: publish with sc1 (relaxed agent atomic STOREs, ack'd at L3, ordered
//   by vmcnt(0)); poll with relaxed agent RMW (coherent by construction, no
//   inv); ONE acquire RMW per tail block before normal reads.

#define TT 8192
#define BB 8
#define NB 32          // compaction roles per row
#define SLICE 256      // tokens per compaction slice
#define NPART 16384    // grid size (= BT/4)
#define NTAIL 257      // 256 compaction roles + 1 scalar role

__device__ __forceinline__ void agent_store(float* p, float v) {
    __hip_atomic_store(p, v, __ATOMIC_RELAXED, __HIP_MEMORY_SCOPE_AGENT);
}

__global__ __launch_bounds__(256) void fused_kernel(
    const float* __restrict__ x, const float* __restrict__ W,
    float* __restrict__ logits,
    float* __restrict__ ws_se, float* __restrict__ ws_sg,
    unsigned int* done,
    float* __restrict__ out_sel, float* __restrict__ out_gw,
    float* __restrict__ out_aux, float* __restrict__ out_z, int max_k)
{
    const int tid  = threadIdx.x;
    const int lane = tid & 63;
    const int wid  = tid >> 6;
    const int tok  = blockIdx.x * 4 + wid;

    __shared__ float s_lg[4];
    __shared__ unsigned int s_ticket;

    // ================= phase 1: wave-per-token logits (proven) ==============
    {
        const float4* xp = reinterpret_cast<const float4*>(x + (size_t)tok * 512 + lane * 8);
        const float4* wp = reinterpret_cast<const float4*>(W + lane * 8);
        float4 x0 = xp[0]; float4 x1 = xp[1];
        float4 w0 = wp[0]; float4 w1 = wp[1];

        double acc = (double)x0.x * w0.x + (double)x0.y * w0.y
                   + (double)x0.z * w0.z + (double)x0.w * w0.w
                   + (double)x1.x * w1.x + (double)x1.y * w1.y
                   + (double)x1.z * w1.z + (double)x1.w * w1.w;

        #pragma unroll
        for (int off = 32; off > 0; off >>= 1)
            acc += __shfl_xor(acc, off, 64);

        if (lane == 0) {
            const float lg = (float)acc;
            agent_store(&logits[tok], lg);   // sc1: lands at L3, no fence
            s_lg[wid] = lg;
        }
    }
    __syncthreads();   // per-wave vmcnt(0) before barrier: sc1 stores ack'd
    if (tid == 0) {
        float se = 0.f, sg = 0.f;
        #pragma unroll
        for (int i = 0; i < 4; ++i) {
            const float lg = s_lg[i];
            se += expf(lg);
            sg += 1.f / (1.f + expf(-lg));
        }
        agent_store(&ws_se[blockIdx.x], se);
        agent_store(&ws_sg[blockIdx.x], sg);
        // Drain this wave's sc1 stores to L3 before publishing the ticket.
        asm volatile("s_waitcnt vmcnt(0)" ::: "memory");
        s_ticket = __hip_atomic_fetch_add(done, 1u, __ATOMIC_RELAXED,
                                          __HIP_MEMORY_SCOPE_AGENT);
    }
    __syncthreads();
    const unsigned int ticket = s_ticket;
    if (ticket < (unsigned)(NPART - NTAIL)) return;

    // ================= phase 2: last 257 finishers do the tail ==============
    if (tid == 0) {
        // RMW poll: coherent by construction (executes at L3), no cache inv.
        // Bounded so a broken mechanism fails validation instead of hanging.
        for (long tries = 0; tries < (1L << 21); ++tries) {
            unsigned int v = __hip_atomic_fetch_add(done, 0u, __ATOMIC_RELAXED,
                                                    __HIP_MEMORY_SCOPE_AGENT);
            if (v >= (unsigned)NPART) break;
            __builtin_amdgcn_s_sleep(8);
        }
        // ONE acquire per tail block: buffer_inv, then normal loads are fresh.
        __hip_atomic_fetch_add(done, 0u, __ATOMIC_ACQUIRE,
                               __HIP_MEMORY_SCOPE_AGENT);
    }
    __syncthreads();

    const int role = (int)ticket - (NPART - NTAIL);   // 0..256

    if (role == 256) {
        // ---- scalar losses from ws partials ----
        float acc8[8];
        #pragma unroll
        for (int r = 0; r < 8; ++r) {
            float s = 0.f;
            #pragma unroll
            for (int k = 0; k < 8; ++k) s += ws_se[r * 2048 + tid + 256 * k];
            acc8[r] = s;
        }
        float sgp = 0.f;
        #pragma unroll
        for (int k = 0; k < 64; ++k) sgp += ws_sg[tid + 256 * k];

        __shared__ float red[9][256];
        #pragma unroll
        for (int r = 0; r < 8; ++r) red[r][tid] = acc8[r];
        red[8][tid] = sgp;
        __syncthreads();
        for (int s = 128; s > 0; s >>= 1) {
            if (tid < s) {
                #pragma unroll
                for (int r = 0; r < 9; ++r) red[r][tid] += red[r][tid + s];
            }
            __syncthreads();
        }
        if (tid == 0) {
            float zz = 0.f;
            #pragma unroll
            for (int r = 0; r < 8; ++r) { float z = logf(red[r][0]); zz += z * z; }
            *out_z = 0.001f * zz / (float)BB;
            float m = red[8][0] / (float)(BB * TT);
            *out_aux = 0.01f * m * (1.f - m);
        }
        return;
    }

    // ---- per-row stable compaction; role owns a 256-token output slice ----
    const int row  = role >> 5;   // /NB
    const int part = role & 31;   // %NB
    const float* rowp = logits + (size_t)row * TT;

    const int base = 32 * tid;
    float4 v0 = *reinterpret_cast<const float4*>(rowp + base);
    float4 v1 = *reinterpret_cast<const float4*>(rowp + base + 4);
    float4 v2 = *reinterpret_cast<const float4*>(rowp + base + 8);
    float4 v3 = *reinterpret_cast<const float4*>(rowp + base + 12);
    float4 v4 = *reinterpret_cast<const float4*>(rowp + base + 16);
    float4 v5 = *reinterpret_cast<const float4*>(rowp + base + 20);
    float4 v6 = *reinterpret_cast<const float4*>(rowp + base + 24);
    float4 v7 = *reinterpret_cast<const float4*>(rowp + base + 28);

    unsigned mask = 0u;
#define CHK(f, b) mask |= ((f >= 0.f) ? 1u : 0u) << (b)
    CHK(v0.x, 0);  CHK(v0.y, 1);  CHK(v0.z, 2);  CHK(v0.w, 3);
    CHK(v1.x, 4);  CHK(v1.y, 5);  CHK(v1.z, 6);  CHK(v1.w, 7);
    CHK(v2.x, 8);  CHK(v2.y, 9);  CHK(v2.z, 10); CHK(v2.w, 11);
    CHK(v3.x, 12); CHK(v3.y, 13); CHK(v3.z, 14); CHK(v3.w, 15);
    CHK(v4.x, 16); CHK(v4.y, 17); CHK(v4.z, 18); CHK(v4.w, 19);
    CHK(v5.x, 20); CHK(v5.y, 21); CHK(v5.z, 22); CHK(v5.w, 23);
    CHK(v6.x, 24); CHK(v6.y, 25); CHK(v6.z, 26); CHK(v6.w, 27);
    CHK(v7.x, 28); CHK(v7.y, 29); CHK(v7.z, 30); CHK(v7.w, 31);
#undef CHK
    const int c_local = __popc(mask);

    int inc = c_local;
    #pragma unroll
    for (int off = 1; off < 64; off <<= 1) {
        int n = __shfl_up(inc, off, 64);
        if (lane >= off) inc += n;
    }
    __shared__ int s_wsum[4];
    __shared__ int s_last[4];
    __shared__ int s_excl[256];
    if (lane == 63) s_wsum[wid] = inc;

    int lastt = mask ? (base + 31 - __clz(mask)) : -1;
    #pragma unroll
    for (int off = 32; off > 0; off >>= 1)
        lastt = max(lastt, __shfl_xor(lastt, off, 64));
    if (lane == 0) s_last[wid] = lastt;
    __syncthreads();

    int woff = 0;
    #pragma unroll
    for (int w = 0; w < 4; ++w) if (w < wid) woff += s_wsum[w];
    const int cnt = s_wsum[0] + s_wsum[1] + s_wsum[2] + s_wsum[3];
    const int excl = woff + (inc - c_local);
    s_excl[tid] = excl;
    const int tok_last = max(max(s_last[0], s_last[1]), max(s_last[2], s_last[3]));
    __syncthreads();

    const int slice0 = s_excl[8 * part];
    const int slice1 = (part == NB - 1) ? cnt : s_excl[8 * part + 8];

    __shared__ unsigned short s_tok[SLICE];
    __shared__ float          s_gwv[SLICE];
    if (tid >= 8 * part && tid < 8 * part + 8) {
        int off = excl - slice0;
#define EMIT(f, i) if ((f) >= 0.f) { s_tok[off] = (unsigned short)(base + (i)); \
                                     s_gwv[off] = 1.f / (1.f + expf(-(f))); ++off; }
        EMIT(v0.x, 0);  EMIT(v0.y, 1);  EMIT(v0.z, 2);  EMIT(v0.w, 3);
        EMIT(v1.x, 4);  EMIT(v1.y, 5);  EMIT(v1.z, 6);  EMIT(v1.w, 7);
        EMIT(v2.x, 8);  EMIT(v2.y, 9);  EMIT(v2.z, 10); EMIT(v2.w, 11);
        EMIT(v3.x, 12); EMIT(v3.y, 13); EMIT(v3.z, 14); EMIT(v3.w, 15);
        EMIT(v4.x, 16); EMIT(v4.y, 17); EMIT(v4.z, 18); EMIT(v4.w, 19);
        EMIT(v5.x, 20); EMIT(v5.y, 21); EMIT(v5.z, 22); EMIT(v5.w, 23);
        EMIT(v6.x, 24); EMIT(v6.y, 25); EMIT(v6.z, 26); EMIT(v6.w, 27);
        EMIT(v7.x, 28); EMIT(v7.y, 29); EMIT(v7.z, 30); EMIT(v7.w, 31);
#undef EMIT
    }
    __syncthreads();

    const int m = slice1 - slice0;
    if (tid < m) {
        out_sel[(size_t)row * max_k + slice0 + tid] = (float)s_tok[tid];
        out_gw [(size_t)row * max_k + slice0 + tid] = s_gwv[tid];
    }

    const int tl = (cnt > 0) ? tok_last : 0;
    const float gw_last = 1.f / (1.f + expf(-rowp[tl]));
    for (int k = cnt + part * SLICE + tid; k < max_k; k += NB * SLICE) {
        out_sel[(size_t)row * max_k + k] = (float)tl;
        out_gw [(size_t)row * max_k + k] = gw_last;
    }
}

extern "C" void kernel_launch(void* const* d_in, const int* in_sizes, int n_in,
                              void* d_out, int out_size, void* d_ws, size_t ws_size,
                              hipStream_t stream)
{
    const float* x = (const float*)d_in[0];
    const float* W = (const float*)d_in[1];

    const int D  = in_sizes[1];          // 512
    const int BT = in_sizes[0] / D;      // 65536
    const int max_k = (out_size - BT - 2) / (2 * BB);

    float* out        = (float*)d_out;
    float* out_sel    = out;
    float* out_gw     = out + (size_t)BB * max_k;
    float* out_logits = out + (size_t)2 * BB * max_k;
    float* out_aux    = out + (size_t)2 * BB * max_k + BT;
    float* out_z      = out_aux + 1;

    unsigned int* done = (unsigned int*)d_ws;
    float* ws_se = (float*)((char*)d_ws + 64);
    float* ws_sg = ws_se + NPART;

    // Reset the finish counter every call (ws is poisoned, never re-poisoned).
    hipMemsetAsync(d_ws, 0, 64, stream);

    fused_kernel<<<NPART, 256, 0, stream>>>(x, W, out_logits, ws_se, ws_sg,
                                            done, out_sel, out_gw,
                                            out_aux, out_z, max_k);
}

// Round 8
// 33.454 us; speedup vs baseline: 14.9591x; 6.5983x over previous
//
#include <hip/hip_runtime.h>
#include <math.h>

// TokenChoiceRouter: B=8, T=8192, D=512 — two launches (r4 structure).
// d_out (float32 flat): [selected B*max_k][gate_weights B*max_k][raw_logits B*T][aux][z]
// ws: [se f32 x8192][sg f32 x8192] per-K1-block (8-token) partials.
// r5-r7 lesson: grid-finish tickets/fences cost 200-660us on gfx950
// (same-line RMW serialization / wbl2+inv storms). Two launches it is.

#define TT 8192
#define BB 8
#define NB 32          // K2 compaction blocks per row
#define SLICE 256      // tokens per K2 block slice
#define NPART 8192     // K1 blocks (= BT/8)

// K1: one wave per TWO tokens — 4 independent float4 loads in flight per
// lane (2x the MLP of wave-per-token) to cover load latency; 2 f64 accs.
__global__ __launch_bounds__(256) void logits_kernel(
    const float* __restrict__ x, const float* __restrict__ W,
    float* __restrict__ logits,
    float* __restrict__ ws_se, float* __restrict__ ws_sg)
{
    const int tid  = threadIdx.x;
    const int lane = tid & 63;
    const int wid  = tid >> 6;
    const int tok0 = (blockIdx.x * 4 + wid) * 2;

    const float4* wp  = reinterpret_cast<const float4*>(W + lane * 8);
    const float4* xp0 = reinterpret_cast<const float4*>(x + (size_t)tok0 * 512 + lane * 8);
    const float4 w0 = wp[0],   w1 = wp[1];
    const float4 a0 = xp0[0],  a1 = xp0[1];      // token tok0
    const float4 b0 = xp0[128], b1 = xp0[129];   // token tok0+1 (+512 floats)

    // f64 accumulation keeps sign decisions aligned with the f64 numpy ref.
    double acc0 = (double)a0.x * w0.x + (double)a0.y * w0.y
                + (double)a0.z * w0.z + (double)a0.w * w0.w
                + (double)a1.x * w1.x + (double)a1.y * w1.y
                + (double)a1.z * w1.z + (double)a1.w * w1.w;
    double acc1 = (double)b0.x * w0.x + (double)b0.y * w0.y
                + (double)b0.z * w0.z + (double)b0.w * w0.w
                + (double)b1.x * w1.x + (double)b1.y * w1.y
                + (double)b1.z * w1.z + (double)b1.w * w1.w;

    #pragma unroll
    for (int off = 32; off > 0; off >>= 1) {
        acc0 += __shfl_xor(acc0, off, 64);
        acc1 += __shfl_xor(acc1, off, 64);
    }

    __shared__ float s_lg[8];
    if (lane == 0) {
        float2 lg2 = make_float2((float)acc0, (float)acc1);
        *reinterpret_cast<float2*>(logits + tok0) = lg2;   // 8B aligned (tok0 even)
        s_lg[wid * 2]     = lg2.x;
        s_lg[wid * 2 + 1] = lg2.y;
    }
    __syncthreads();
    if (tid == 0) {
        float se = 0.f, sg = 0.f;
        #pragma unroll
        for (int i = 0; i < 8; ++i) {
            const float lg = s_lg[i];
            se += expf(lg);
            sg += 1.f / (1.f + expf(-lg));
        }
        ws_se[blockIdx.x] = se;
        ws_sg[blockIdx.x] = sg;
    }
}

// K2: 256 compaction blocks (32/row) + 1 scalar block. (r4-proven body)
__global__ __launch_bounds__(256) void finish_kernel(
    const float* __restrict__ logits,
    const float* __restrict__ ws_se, const float* __restrict__ ws_sg,
    float* __restrict__ out_sel, float* __restrict__ out_gw,
    float* __restrict__ out_aux, float* __restrict__ out_z, int max_k)
{
    const int tid  = threadIdx.x;
    const int lane = tid & 63;
    const int wid  = tid >> 6;       // 0..3

    if (blockIdx.x == BB * NB) {
        // ---- scalar losses from ws partials (1024 se/row, 8192 sg total) ----
        float acc8[8];
        #pragma unroll
        for (int r = 0; r < 8; ++r) {
            float s = 0.f;
            #pragma unroll
            for (int k = 0; k < 4; ++k) s += ws_se[r * 1024 + tid + 256 * k];
            acc8[r] = s;
        }
        float sgp = 0.f;
        #pragma unroll
        for (int k = 0; k < 32; ++k) sgp += ws_sg[tid + 256 * k];

        __shared__ float red[9][256];
        #pragma unroll
        for (int r = 0; r < 8; ++r) red[r][tid] = acc8[r];
        red[8][tid] = sgp;
        __syncthreads();
        for (int s = 128; s > 0; s >>= 1) {
            if (tid < s) {
                #pragma unroll
                for (int r = 0; r < 9; ++r) red[r][tid] += red[r][tid + s];
            }
            __syncthreads();
        }
        if (tid == 0) {
            float zz = 0.f;
            #pragma unroll
            for (int r = 0; r < 8; ++r) { float z = logf(red[r][0]); zz += z * z; }
            *out_z = 0.001f * zz / (float)BB;
            float m = red[8][0] / (float)(BB * TT);
            *out_aux = 0.01f * m * (1.f - m);
        }
        return;
    }

    // ---- per-row stable compaction; block owns a 256-token output slice ----
    const int row  = blockIdx.x >> 5;   // /NB
    const int part = blockIdx.x & 31;   // %NB
    const float* rowp = logits + (size_t)row * TT;

    const int base = 32 * tid;
    float4 v0 = *reinterpret_cast<const float4*>(rowp + base);
    float4 v1 = *reinterpret_cast<const float4*>(rowp + base + 4);
    float4 v2 = *reinterpret_cast<const float4*>(rowp + base + 8);
    float4 v3 = *reinterpret_cast<const float4*>(rowp + base + 12);
    float4 v4 = *reinterpret_cast<const float4*>(rowp + base + 16);
    float4 v5 = *reinterpret_cast<const float4*>(rowp + base + 20);
    float4 v6 = *reinterpret_cast<const float4*>(rowp + base + 24);
    float4 v7 = *reinterpret_cast<const float4*>(rowp + base + 28);

    unsigned mask = 0u;
#define CHK(f, b) mask |= ((f >= 0.f) ? 1u : 0u) << (b)
    CHK(v0.x, 0);  CHK(v0.y, 1);  CHK(v0.z, 2);  CHK(v0.w, 3);
    CHK(v1.x, 4);  CHK(v1.y, 5);  CHK(v1.z, 6);  CHK(v1.w, 7);
    CHK(v2.x, 8);  CHK(v2.y, 9);  CHK(v2.z, 10); CHK(v2.w, 11);
    CHK(v3.x, 12); CHK(v3.y, 13); CHK(v3.z, 14); CHK(v3.w, 15);
    CHK(v4.x, 16); CHK(v4.y, 17); CHK(v4.z, 18); CHK(v4.w, 19);
    CHK(v5.x, 20); CHK(v5.y, 21); CHK(v5.z, 22); CHK(v5.w, 23);
    CHK(v6.x, 24); CHK(v6.y, 25); CHK(v6.z, 26); CHK(v6.w, 27);
    CHK(v7.x, 28); CHK(v7.y, 29); CHK(v7.z, 30); CHK(v7.w, 31);
#undef CHK
    const int c_local = __popc(mask);

    int inc = c_local;
    #pragma unroll
    for (int off = 1; off < 64; off <<= 1) {
        int n = __shfl_up(inc, off, 64);
        if (lane >= off) inc += n;
    }
    __shared__ int s_wsum[4];
    __shared__ int s_last[4];
    __shared__ int s_excl[256];
    if (lane == 63) s_wsum[wid] = inc;

    int lastt = mask ? (base + 31 - __clz(mask)) : -1;
    #pragma unroll
    for (int off = 32; off > 0; off >>= 1)
        lastt = max(lastt, __shfl_xor(lastt, off, 64));
    if (lane == 0) s_last[wid] = lastt;
    __syncthreads();

    int woff = 0;
    #pragma unroll
    for (int w = 0; w < 4; ++w) if (w < wid) woff += s_wsum[w];
    const int cnt = s_wsum[0] + s_wsum[1] + s_wsum[2] + s_wsum[3];
    const int excl = woff + (inc - c_local);
    s_excl[tid] = excl;
    const int tok_last = max(max(s_last[0], s_last[1]), max(s_last[2], s_last[3]));
    __syncthreads();

    const int slice0 = s_excl[8 * part];
    const int slice1 = (part == NB - 1) ? cnt : s_excl[8 * part + 8];

    __shared__ unsigned short s_tok[SLICE];
    __shared__ float          s_gwv[SLICE];
    if (tid >= 8 * part && tid < 8 * part + 8) {
        int off = excl - slice0;
#define EMIT(f, i) if ((f) >= 0.f) { s_tok[off] = (unsigned short)(base + (i)); \
                                     s_gwv[off] = 1.f / (1.f + expf(-(f))); ++off; }
        EMIT(v0.x, 0);  EMIT(v0.y, 1);  EMIT(v0.z, 2);  EMIT(v0.w, 3);
        EMIT(v1.x, 4);  EMIT(v1.y, 5);  EMIT(v1.z, 6);  EMIT(v1.w, 7);
        EMIT(v2.x, 8);  EMIT(v2.y, 9);  EMIT(v2.z, 10); EMIT(v2.w, 11);
        EMIT(v3.x, 12); EMIT(v3.y, 13); EMIT(v3.z, 14); EMIT(v3.w, 15);
        EMIT(v4.x, 16); EMIT(v4.y, 17); EMIT(v4.z, 18); EMIT(v4.w, 19);
        EMIT(v5.x, 20); EMIT(v5.y, 21); EMIT(v5.z, 22); EMIT(v5.w, 23);
        EMIT(v6.x, 24); EMIT(v6.y, 25); EMIT(v6.z, 26); EMIT(v6.w, 27);
        EMIT(v7.x, 28); EMIT(v7.y, 29); EMIT(v7.z, 30); EMIT(v7.w, 31);
#undef EMIT
    }
    __syncthreads();

    const int m = slice1 - slice0;
    if (tid < m) {
        out_sel[(size_t)row * max_k + slice0 + tid] = (float)s_tok[tid];
        out_gw [(size_t)row * max_k + slice0 + tid] = s_gwv[tid];
    }

    const int tl = (cnt > 0) ? tok_last : 0;
    const float gw_last = 1.f / (1.f + expf(-rowp[tl]));
    for (int k = cnt + part * SLICE + tid; k < max_k; k += NB * SLICE) {
        out_sel[(size_t)row * max_k + k] = (float)tl;
        out_gw [(size_t)row * max_k + k] = gw_last;
    }
}

extern "C" void kernel_launch(void* const* d_in, const int* in_sizes, int n_in,
                              void* d_out, int out_size, void* d_ws, size_t ws_size,
                              hipStream_t stream)
{
    const float* x = (const float*)d_in[0];
    const float* W = (const float*)d_in[1];

    const int D  = in_sizes[1];          // 512
    const int BT = in_sizes[0] / D;      // 65536
    const int max_k = (out_size - BT - 2) / (2 * BB);

    float* out        = (float*)d_out;
    float* out_sel    = out;
    float* out_gw     = out + (size_t)BB * max_k;
    float* out_logits = out + (size_t)2 * BB * max_k;
    float* out_aux    = out + (size_t)2 * BB * max_k + BT;
    float* out_z      = out_aux + 1;

    float* ws_se = (float*)d_ws;
    float* ws_sg = ws_se + NPART;

    // K1: one wave per two tokens (2x MLP) + per-block stat partials.
    logits_kernel<<<BT / 8, 256, 0, stream>>>(x, W, out_logits, ws_se, ws_sg);

    // K2: 256 compaction blocks + 1 scalar block, single launch.
    finish_kernel<<<BB * NB + 1, 256, 0, stream>>>(out_logits, ws_se, ws_sg,
                                                   out_sel, out_gw,
                                                   out_aux, out_z, max_k);
}